// Round 12
// baseline (27.057 us; speedup 1.0000x reference)
//
#include <hip/hip_runtime.h>
#include <hip/hip_bf16.h>

#define BB 4096   // batch
#define DD 64     // event dim
#define HH 512    // hidden

typedef short short8 __attribute__((ext_vector_type(8)));   // 8 bf16
typedef float f32x4  __attribute__((ext_vector_type(4)));
typedef __hip_bfloat16 bf16;

// branchless fast tanh: 1 - 2/(1+e^{2x}); exact limits at +-inf
__device__ __forceinline__ float tanh_fast(float x) {
    float e = __expf(2.0f * x);
    return 1.0f - __fdividef(2.0f, 1.0f + e);
}

// swizzled LDS bf16 store: 8-elem chunk XOR'd with row&7 (write side)
__device__ __forceinline__ void st_swz(bf16* base, int row, int col, int rs, float v) {
    base[row * rs + ((((col >> 3) ^ (row & 7))) << 3) + (col & 7)] = __float2bfloat16(v);
}

// single 1KB fragment load (proven R10)
#define GLD1(dst, addr)                                                      \
  asm volatile("global_load_dwordx4 %0, %1, off" : "=&v"(dst) : "v"(addr))

// 2KB entry = 2 x 1KB
#define GLD2(e0, e1, addr)                                                   \
  asm volatile("global_load_dwordx4 %0, %2, off\n\t"                         \
               "global_load_dwordx4 %1, %2, off offset:1024"                 \
               : "=&v"(e0), "=&v"(e1) : "v"(addr))

// 4KB entry = 4 x 1KB (proven R10)
#define GLD4(e0, e1, e2, e3, addr)                                           \
  asm volatile("global_load_dwordx4 %0, %4, off\n\t"                         \
               "global_load_dwordx4 %1, %4, off offset:1024\n\t"             \
               "global_load_dwordx4 %2, %4, off offset:2048\n\t"             \
               "global_load_dwordx4 %3, %4, off offset:3072"                 \
               : "=&v"(e0), "=&v"(e1), "=&v"(e2), "=&v"(e3) : "v"(addr))

// counted wait + compiler motion fence (rule 18)
#define WAITV(n)                                                             \
  do { asm volatile("s_waitcnt vmcnt(" #n ")" ::: "memory");                 \
       __builtin_amdgcn_sched_barrier(0); } while (0)

// ===========================================================================
// Packed weights (16-col x 32-k tiles, tile = 512 elems = 1KB; lane l:
// kq=l>>4, r=l&15 owns B[col=base+r][k=kbase+kq*8+j], j=0..7 = 16B).
//   W1p: T = w*4 + s*2 + f   (w 0..15, s 0..1, f 0..1)  col=(w*2+f)*16+r
//   W2p: T = cw*16 + s       (cw 0..31, s 0..15)        col=cw*16+r
//   Pp : T = cw*16 + s       outcol k=cw*16+r, reduce j=s*32+kq*8+jj
//   W3p: T = q*4 + f         (q 0..15, f 0..3)          col=f*16+r, k=q*32+..
// ===========================================================================
__global__ __launch_bounds__(256) void prep_kernel(
    const float* __restrict__ t, const float* __restrict__ W1,
    const float* __restrict__ b1, const float* __restrict__ W2,
    const float* __restrict__ W3, const float* __restrict__ b3,
    bf16* __restrict__ W1p, bf16* __restrict__ W2p, bf16* __restrict__ W3p,
    bf16* __restrict__ Pp, float* __restrict__ b1eff, float* __restrict__ out)
{
    const int tid  = threadIdx.x;
    const int bx   = blockIdx.x;
    const int lane = tid & 63;
    const int r    = lane & 15;
    const int kq   = lane >> 4;

    if (bx < 160) {
        int T = bx * 4 + (tid >> 6);     // 0..639
        const float* src;
        bf16* dst;
        int stride;
        if (T < 64) {            // W1p
            int w = T >> 2, s = (T >> 1) & 1, f = T & 1;
            src = W1 + (size_t)(s * 32 + kq * 8) * HH + (w * 2 + f) * 16 + r;
            stride = HH;
            dst = W1p + (size_t)T * 512 + lane * 8;
        } else if (T < 576) {    // W2p
            int tt = T - 64;
            int cw = tt >> 4, s = tt & 15;
            src = W2 + (size_t)(s * 32 + kq * 8) * HH + cw * 16 + r;
            stride = HH;
            dst = W2p + (size_t)tt * 512 + lane * 8;
        } else {                 // W3p
            int tt = T - 576;
            int q = tt >> 2, f = tt & 3;
            src = W3 + (size_t)(q * 32 + kq * 8) * DD + f * 16 + r;
            stride = DD;
            dst = W3p + (size_t)tt * 512 + lane * 8;
        }
        short8 v;
#pragma unroll
        for (int j = 0; j < 8; ++j)
            v[j] = (short)__bfloat16_as_ushort(__float2bfloat16(src[(size_t)j * stride]));
        *(short8*)dst = v;
    } else if (bx < 288) {
        // Pp tile pt: out-col k = cw*16+r, reduce j = s*32+kq*8+jj
        int pt = (bx - 160) * 4 + (tid >> 6);    // 0..511
        int cw = pt >> 4, s = pt & 15;
        int k  = cw * 16 + r;
        int j0 = s * 32 + kq * 8;
        float acc[8] = {};
        const float* w3row = W3 + (size_t)k * DD;
        for (int d = 0; d < DD; ++d) {
            float w3 = w3row[d];
            const float4* w1p4 = (const float4*)(W1 + (size_t)d * HH + j0);
            float4 x = w1p4[0], y = w1p4[1];
            acc[0] += x.x * w3; acc[1] += x.y * w3;
            acc[2] += x.z * w3; acc[3] += x.w * w3;
            acc[4] += y.x * w3; acc[5] += y.y * w3;
            acc[6] += y.z * w3; acc[7] += y.w * w3;
        }
        short8 v;
#pragma unroll
        for (int j = 0; j < 8; ++j)
            v[j] = (short)__bfloat16_as_ushort(
                __float2bfloat16(acc[j] * W2[(size_t)(j0 + j) * HH + k]));
        *(short8*)(Pp + (size_t)pt * 512 + lane * 8) = v;
    } else if (bx == 288) {
        float tv = t[0];
        b1eff[tid]       = b1[tid]       + tv * W1[(size_t)64 * HH + tid];
        b1eff[tid + 256] = b1[tid + 256] + tv * W1[(size_t)64 * HH + tid + 256];
    } else {
        // init output: v region = b3 broadcast, trace region = 0
        int idx = (bx - 289) * 1024 + tid * 4;   // 260 blocks, exact cover
        if (idx < BB * DD) {
            int col = idx & 63;
            *(float4*)(out + idx) =
                make_float4(b3[col], b3[col + 1], b3[col + 2], b3[col + 3]);
        } else {
            *(float4*)(out + idx) = make_float4(0.f, 0.f, 0.f, 0.f);
        }
    }
}

// ---------------------------------------------------------------------------
// fused_rows: 256 blocks x 1024 threads (16 waves). bid = rt*2 + ch:
// 32 batch rows (rt), column-half ch. Full h1/at (32x512) per block;
// L2/E stream the ch-half of W2p/Pp (wave = 16-col strip, 2 rowgroups ->
// 2 MFMA per 1KB fragment, 2x R10's intensity). L3: 16 waves = 8 k-chunks
// x 2 row-halves. v/trace combine via fp32 atomicAdd onto prep-init out.
// ---------------------------------------------------------------------------
__global__ __launch_bounds__(1024, 2) void fused_rows(
    const float* __restrict__ z, const bf16* __restrict__ W1p,
    const bf16* __restrict__ W2p, const bf16* __restrict__ W3p,
    const bf16* __restrict__ Pp, const float* __restrict__ b1eff,
    const float* __restrict__ b2,
    float* __restrict__ outV, float* __restrict__ outTr)
{
    __shared__ alignas(16) char smem[88064];
    bf16* zt   = (bf16*)smem;                 // [32][64]  swizzled (4 KB)
    bf16* h1   = (bf16*)(smem + 4096);        // [32][512] swizzled (32 KB)
    bf16* at   = (bf16*)(smem + 36864);       // [32][512] swizzled (32 KB)
    bf16* h2   = (bf16*)(smem + 69632);       // [32][256] swizzled (16 KB)
    float* trp = (float*)(smem + 86016);      // [16][32]           (2 KB)
    float* vp  = (float*)smem;                // [8][32][64] overlays zt+h1+at

    const int tid  = threadIdx.x;
    const int wid  = tid >> 6;                // 0..15
    const int lane = tid & 63;
    const int r    = lane & 15;
    const int kq   = lane >> 4;
    const int rx   = r & 7;
    const int laneE = lane * 8;
    const int rt   = blockIdx.x >> 1;
    const int ch   = blockIdx.x & 1;
    const int bm   = rt * 32;

    // ---- preload biases before any asm loads; pin them live ----
    float bias1[2];
#pragma unroll
    for (int f = 0; f < 2; ++f) bias1[f] = b1eff[wid * 32 + f * 16 + r];
    float bias2 = b2[ch * 256 + wid * 16 + r];
    asm volatile("" :: "v"(bias1[0]), "v"(bias1[1]), "v"(bias2));

    // ---- stage z: 32x64 f32 -> bf16 swizzled (2 elems/thread) ----
    {
        int i = tid * 2;
        int row = i >> 6, col = i & 63;
        float2 v = *(const float2*)(z + (size_t)(bm + row) * DD + col);
        st_swz(zt, row, col,     64, v.x);
        st_swz(zt, row, col + 1, 64, v.y);
    }

    // ---- L1 prefetch: wave strip = 32 cols, 2 entries (K=64) ----
    short8 q0, q1, q2, q3, p0, p1;
    const bf16* Wb1 = W1p + (size_t)wid * 2048 + laneE;
    GLD2(q0, q1, Wb1);
    GLD2(p0, p1, Wb1 + 1024);
    __syncthreads();

    // ---- L1: h1 = tanh(z @ W1 + b1eff); a = 1-h1^2 (2 rowgroups) ----
    f32x4 acc1[2][2] = {};    // [g][f]
    WAITV(2);
#pragma unroll
    for (int g = 0; g < 2; ++g) {
        short8 av = *(const short8*)(zt + (g * 16 + r) * 64 + ((kq ^ rx) << 3));
        acc1[g][0] = __builtin_amdgcn_mfma_f32_16x16x32_bf16(av, q0, acc1[g][0], 0, 0, 0);
        acc1[g][1] = __builtin_amdgcn_mfma_f32_16x16x32_bf16(av, q1, acc1[g][1], 0, 0, 0);
    }
    WAITV(0);
#pragma unroll
    for (int g = 0; g < 2; ++g) {
        short8 av = *(const short8*)(zt + (g * 16 + r) * 64 + (((4 + kq) ^ rx) << 3));
        acc1[g][0] = __builtin_amdgcn_mfma_f32_16x16x32_bf16(av, p0, acc1[g][0], 0, 0, 0);
        acc1[g][1] = __builtin_amdgcn_mfma_f32_16x16x32_bf16(av, p1, acc1[g][1], 0, 0, 0);
    }
    // L2 ring prologue (issue before epilogue so HBM/L2 latency hides)
    short8 rb[3];
    const bf16* Wb2 = W2p + (size_t)(ch * 16 + wid) * 8192 + laneE;
    GLD1(rb[0], Wb2);
    GLD1(rb[1], Wb2 + 512);
    // L1 epilogue
#pragma unroll
    for (int g = 0; g < 2; ++g)
#pragma unroll
        for (int f = 0; f < 2; ++f) {
            int col = wid * 32 + f * 16 + r;
#pragma unroll
            for (int v = 0; v < 4; ++v) {
                int row = g * 16 + kq * 4 + v;
                float h = tanh_fast(acc1[g][f][v] + bias1[f]);
                st_swz(h1, row, col, 512, h);
                st_swz(at, row, col, 512, fmaf(-h, h, 1.0f));
            }
        }
    __syncthreads();

    // ---- L2: h2 = tanh(h1 @ W2 + b2), this block's 256-col half ----
    f32x4 bsq[2];
    {
        f32x4 acc2[2] = {};
#pragma unroll
        for (int s = 0; s < 16; ++s) {
            if (s + 2 < 16)      { GLD1(rb[(s + 2) % 3], Wb2 + (s + 2) * 512); WAITV(2); }
            else if (s + 1 < 16) { WAITV(1); }
            else                 { WAITV(0); }
#pragma unroll
            for (int g = 0; g < 2; ++g) {
                short8 av = *(const short8*)(h1 + (g * 16 + r) * 512 + (((s * 4 + kq) ^ rx) << 3));
                acc2[g] = __builtin_amdgcn_mfma_f32_16x16x32_bf16(av, rb[s % 3], acc2[g], 0, 0, 0);
            }
        }
        // E ring prologue
        const bf16* WbE = Pp + (size_t)(ch * 16 + wid) * 8192 + laneE;
        GLD1(rb[0], WbE);
        GLD1(rb[1], WbE + 512);
        // epilogue
        int colL = wid * 16 + r;
#pragma unroll
        for (int g = 0; g < 2; ++g)
#pragma unroll
            for (int v = 0; v < 4; ++v) {
                int row = g * 16 + kq * 4 + v;
                float h = tanh_fast(acc2[g][v] + bias2);
                st_swz(h2, row, colL, 256, h);
                bsq[g][v] = fmaf(-h, h, 1.0f);
            }
    }

    // ---- E: V = a @ P (half cols); trace partials (no barrier) ----
    {
        const bf16* WbE = Pp + (size_t)(ch * 16 + wid) * 8192 + laneE;
        f32x4 accE[2] = {};
#pragma unroll
        for (int s = 0; s < 16; ++s) {
            if (s + 2 < 16)      { GLD1(rb[(s + 2) % 3], WbE + (s + 2) * 512); WAITV(2); }
            else if (s + 1 < 16) { WAITV(1); }
            else                 { WAITV(0); }
#pragma unroll
            for (int g = 0; g < 2; ++g) {
                short8 av = *(const short8*)(at + (g * 16 + r) * 512 + (((s * 4 + kq) ^ rx) << 3));
                accE[g] = __builtin_amdgcn_mfma_f32_16x16x32_bf16(av, rb[s % 3], accE[g], 0, 0, 0);
            }
        }
        // L3 prefetch (one 4KB entry per wave)
        const int kw = wid & 7;
        const bf16* Wb3 = W3p + (size_t)(ch * 8 + kw) * 2048 + laneE;
        GLD4(q0, q1, q2, q3, Wb3);
        // trace partial: p(row) = sum over this wave's 16 cols of V*bsq
#pragma unroll
        for (int g = 0; g < 2; ++g)
#pragma unroll
            for (int v = 0; v < 4; ++v) {
                float p = accE[g][v] * bsq[g][v];
                p += __shfl_xor(p, 1);
                p += __shfl_xor(p, 2);
                p += __shfl_xor(p, 4);
                p += __shfl_xor(p, 8);
                if (r == 0) trp[wid * 32 + g * 16 + kq * 4 + v] = p;
            }
    }
    __syncthreads();   // h1/at reads done -> vp overlay safe; h2 visible

    // ---- L3: v-partial = h2 @ W3 (this half's k); 8 kw x 2 row-halves ----
    {
        const int kw = wid & 7, rp = wid >> 3;
        f32x4 c0 = {}, c1 = {}, c2 = {}, c3 = {};
        WAITV(0);
        short8 av = *(const short8*)(h2 + (rp * 16 + r) * 256 + (((kw * 4 + kq) ^ rx) << 3));
        c0 = __builtin_amdgcn_mfma_f32_16x16x32_bf16(av, q0, c0, 0, 0, 0);
        c1 = __builtin_amdgcn_mfma_f32_16x16x32_bf16(av, q1, c1, 0, 0, 0);
        c2 = __builtin_amdgcn_mfma_f32_16x16x32_bf16(av, q2, c2, 0, 0, 0);
        c3 = __builtin_amdgcn_mfma_f32_16x16x32_bf16(av, q3, c3, 0, 0, 0);
#pragma unroll
        for (int v = 0; v < 4; ++v) {
            int row = rp * 16 + kq * 4 + v;
            vp[kw * 2048 + row * 64 + 0 * 16 + r] = c0[v];
            vp[kw * 2048 + row * 64 + 1 * 16 + r] = c1[v];
            vp[kw * 2048 + row * 64 + 2 * 16 + r] = c2[v];
            vp[kw * 2048 + row * 64 + 3 * 16 + r] = c3[v];
        }
    }
    __syncthreads();

    // ---- final: reduce 8 k-chunk partials; atomicAdd v and trace ----
#pragma unroll
    for (int it = 0; it < 2; ++it) {
        int i = it * 1024 + tid;
        int row = i >> 6, col = i & 63;
        float s = 0.f;
#pragma unroll
        for (int kw = 0; kw < 8; ++kw) s += vp[kw * 2048 + i];
        atomicAdd(outV + (size_t)(bm + row) * DD + col, s);
    }
    if (tid < 32) {
        float s = 0.f;
#pragma unroll
        for (int w = 0; w < 16; ++w) s += trp[w * 32 + tid];
        atomicAdd(outTr + bm + tid, -s);
    }
}

extern "C" void kernel_launch(void* const* d_in, const int* in_sizes, int n_in,
                              void* d_out, int out_size, void* d_ws, size_t ws_size,
                              hipStream_t stream)
{
    const float* z  = (const float*)d_in[0];
    const float* t  = (const float*)d_in[2];
    const float* W1 = (const float*)d_in[3];
    const float* b1 = (const float*)d_in[4];
    const float* W2 = (const float*)d_in[5];
    const float* b2 = (const float*)d_in[6];
    const float* W3 = (const float*)d_in[7];
    const float* b3 = (const float*)d_in[8];
    float* out = (float*)d_out;                 // v [4096*64] then dlogp [4096]
    float* out_tr = out + (size_t)BB * DD;

    char* w = (char*)d_ws;
    auto alloc = [&](size_t bytes) {
        char* p = w;
        w += (bytes + 255) & ~(size_t)255;
        return p;
    };
    bf16* W1p   = (bf16*)alloc((size_t)64  * 512 * 2);
    bf16* W2p   = (bf16*)alloc((size_t)512 * 512 * 2);
    bf16* W3p   = (bf16*)alloc((size_t)64  * 512 * 2);
    bf16* Pp    = (bf16*)alloc((size_t)512 * 512 * 2);
    float* b1eff = (float*)alloc((size_t)HH * 4);

    // prep: packs + P + b1eff + output init (v=b3 broadcast, trace=0)
    prep_kernel<<<549, 256, 0, stream>>>(t, W1, b1, W2, W3, b3,
                                         W1p, W2p, W3p, Pp, b1eff, out);
    fused_rows<<<128 * 2, 1024, 0, stream>>>(z, W1p, W2p, W3p, Pp,
                                             b1eff, b2, out, out_tr);
}

// Round 13
// 26.567 us; speedup vs baseline: 1.0184x; 1.0184x over previous
//
#include <hip/hip_runtime.h>
#include <hip/hip_bf16.h>

#define BB 4096   // batch
#define DD 64     // event dim
#define HH 512    // hidden

typedef short short8 __attribute__((ext_vector_type(8)));   // 8 bf16
typedef float f32x4  __attribute__((ext_vector_type(4)));
typedef __hip_bfloat16 bf16;

// branchless fast tanh: 1 - 2/(1+e^{2x}); exact limits at +-inf
__device__ __forceinline__ float tanh_fast(float x) {
    float e = __expf(2.0f * x);
    return 1.0f - __fdividef(2.0f, 1.0f + e);
}

// swizzled LDS bf16 store: 8-elem chunk XOR'd with row&7 (write side)
__device__ __forceinline__ void st_swz(bf16* base, int row, int col, int rs, float v) {
    base[row * rs + ((((col >> 3) ^ (row & 7))) << 3) + (col & 7)] = __float2bfloat16(v);
}

// single 1KB fragment load (proven R10/R12)
#define GLD1(dst, addr)                                                      \
  asm volatile("global_load_dwordx4 %0, %1, off" : "=&v"(dst) : "v"(addr))

// 2KB entry = 2 x 1KB
#define GLD2(e0, e1, addr)                                                   \
  asm volatile("global_load_dwordx4 %0, %2, off\n\t"                         \
               "global_load_dwordx4 %1, %2, off offset:1024"                 \
               : "=&v"(e0), "=&v"(e1) : "v"(addr))

// 4KB entry = 4 x 1KB
#define GLD4(e0, e1, e2, e3, addr)                                           \
  asm volatile("global_load_dwordx4 %0, %4, off\n\t"                         \
               "global_load_dwordx4 %1, %4, off offset:1024\n\t"             \
               "global_load_dwordx4 %2, %4, off offset:2048\n\t"             \
               "global_load_dwordx4 %3, %4, off offset:3072"                 \
               : "=&v"(e0), "=&v"(e1), "=&v"(e2), "=&v"(e3) : "v"(addr))

// counted wait + compiler motion fence (rule 18)
#define WAITV(n)                                                             \
  do { asm volatile("s_waitcnt vmcnt(" #n ")" ::: "memory");                 \
       __builtin_amdgcn_sched_barrier(0); } while (0)

// LDS-only barrier: raw s_barrier with lgkmcnt drain but NO vmcnt drain --
// in-flight global prefetches survive (T4). All inter-phase data is in LDS.
#define LGKMBAR()                                                            \
  do { asm volatile("s_waitcnt lgkmcnt(0)" ::: "memory");                    \
       __builtin_amdgcn_s_barrier();                                         \
       __builtin_amdgcn_sched_barrier(0); } while (0)

// ===========================================================================
// Packed weights (16-col x 32-k tiles, tile = 512 elems = 1KB; lane l:
// kq=l>>4, r=l&15 owns B[col=base+r][k=kbase+kq*8+j], j=0..7 = 16B).
//   W1p: T = w*4 + s*2 + f   (w 0..15, s 0..1, f 0..1)  col=(w*2+f)*16+r
//   W2p: T = cw*16 + s       (cw 0..31, s 0..15)        col=cw*16+r
//   Pp : T = cw*16 + s       outcol k=cw*16+r, reduce j=s*32+kq*8+jj
//   W3p: T = q*4 + f         (q 0..15, f 0..3)          col=f*16+r, k=q*32+..
// ===========================================================================
__global__ __launch_bounds__(256) void prep_kernel(
    const float* __restrict__ t, const float* __restrict__ W1,
    const float* __restrict__ b1, const float* __restrict__ W2,
    const float* __restrict__ W3, const float* __restrict__ b3,
    bf16* __restrict__ W1p, bf16* __restrict__ W2p, bf16* __restrict__ W3p,
    bf16* __restrict__ Pp, float* __restrict__ b1eff, float* __restrict__ out)
{
    const int tid  = threadIdx.x;
    const int bx   = blockIdx.x;
    const int lane = tid & 63;
    const int r    = lane & 15;
    const int kq   = lane >> 4;

    if (bx < 160) {
        int T = bx * 4 + (tid >> 6);     // 0..639
        const float* src;
        bf16* dst;
        int stride;
        if (T < 64) {            // W1p
            int w = T >> 2, s = (T >> 1) & 1, f = T & 1;
            src = W1 + (size_t)(s * 32 + kq * 8) * HH + (w * 2 + f) * 16 + r;
            stride = HH;
            dst = W1p + (size_t)T * 512 + lane * 8;
        } else if (T < 576) {    // W2p
            int tt = T - 64;
            int cw = tt >> 4, s = tt & 15;
            src = W2 + (size_t)(s * 32 + kq * 8) * HH + cw * 16 + r;
            stride = HH;
            dst = W2p + (size_t)tt * 512 + lane * 8;
        } else {                 // W3p
            int tt = T - 576;
            int q = tt >> 2, f = tt & 3;
            src = W3 + (size_t)(q * 32 + kq * 8) * DD + f * 16 + r;
            stride = DD;
            dst = W3p + (size_t)tt * 512 + lane * 8;
        }
        short8 v;
#pragma unroll
        for (int j = 0; j < 8; ++j)
            v[j] = (short)__bfloat16_as_ushort(__float2bfloat16(src[(size_t)j * stride]));
        *(short8*)dst = v;
    } else if (bx < 288) {
        // Pp tile pt: out-col k = cw*16+r, reduce j = s*32+kq*8+jj
        int pt = (bx - 160) * 4 + (tid >> 6);    // 0..511
        int cw = pt >> 4, s = pt & 15;
        int k  = cw * 16 + r;
        int j0 = s * 32 + kq * 8;
        float acc[8] = {};
        const float* w3row = W3 + (size_t)k * DD;
        for (int d = 0; d < DD; ++d) {
            float w3 = w3row[d];
            const float4* w1p4 = (const float4*)(W1 + (size_t)d * HH + j0);
            float4 x = w1p4[0], y = w1p4[1];
            acc[0] += x.x * w3; acc[1] += x.y * w3;
            acc[2] += x.z * w3; acc[3] += x.w * w3;
            acc[4] += y.x * w3; acc[5] += y.y * w3;
            acc[6] += y.z * w3; acc[7] += y.w * w3;
        }
        short8 v;
#pragma unroll
        for (int j = 0; j < 8; ++j)
            v[j] = (short)__bfloat16_as_ushort(
                __float2bfloat16(acc[j] * W2[(size_t)(j0 + j) * HH + k]));
        *(short8*)(Pp + (size_t)pt * 512 + lane * 8) = v;
    } else if (bx == 288) {
        float tv = t[0];
        b1eff[tid]       = b1[tid]       + tv * W1[(size_t)64 * HH + tid];
        b1eff[tid + 256] = b1[tid + 256] + tv * W1[(size_t)64 * HH + tid + 256];
    } else {
        // init output: v region = b3 broadcast, trace region = 0
        int idx = (bx - 289) * 1024 + tid * 4;   // 260 blocks, exact cover
        if (idx < BB * DD) {
            int col = idx & 63;
            *(float4*)(out + idx) =
                make_float4(b3[col], b3[col + 1], b3[col + 2], b3[col + 3]);
        } else {
            *(float4*)(out + idx) = make_float4(0.f, 0.f, 0.f, 0.f);
        }
    }
}

// ---------------------------------------------------------------------------
// fused_rows: 256 blocks x 1024 threads (16 waves). bid = rt*2 + ch:
// 32 batch rows (rt), column-half ch. L1 -> [L2||E merged, one 16-step
// loop, dual 4-slot/3-ahead asm rings, counted vmcnt] -> L3.
// Barriers are raw s_barrier + lgkmcnt(0) (prefetches survive).
// v/trace combine via fp32 atomicAdd onto prep-initialized out.
// ---------------------------------------------------------------------------
__global__ __launch_bounds__(1024, 2) void fused_rows(
    const float* __restrict__ z, const bf16* __restrict__ W1p,
    const bf16* __restrict__ W2p, const bf16* __restrict__ W3p,
    const bf16* __restrict__ Pp, const float* __restrict__ b1eff,
    const float* __restrict__ b2,
    float* __restrict__ outV, float* __restrict__ outTr)
{
    __shared__ alignas(16) char smem[88064];
    bf16* zt   = (bf16*)smem;                 // [32][64]  swizzled (4 KB)
    bf16* h1   = (bf16*)(smem + 4096);        // [32][512] swizzled (32 KB)
    bf16* at   = (bf16*)(smem + 36864);       // [32][512] swizzled (32 KB)
    bf16* h2   = (bf16*)(smem + 69632);       // [32][256] swizzled (16 KB)
    float* trp = (float*)(smem + 86016);      // [16][32]           (2 KB)
    float* vp  = (float*)smem;                // [8][32][64] overlays zt+h1+at

    const int tid  = threadIdx.x;
    const int wid  = tid >> 6;                // 0..15
    const int lane = tid & 63;
    const int r    = lane & 15;
    const int kq   = lane >> 4;
    const int rx   = r & 7;
    const int laneE = lane * 8;
    const int rt   = blockIdx.x >> 1;
    const int ch   = blockIdx.x & 1;
    const int bm   = rt * 32;

    // ---- preload biases before any asm loads; pin them live ----
    float bias1[2];
#pragma unroll
    for (int f = 0; f < 2; ++f) bias1[f] = b1eff[wid * 32 + f * 16 + r];
    float bias2 = b2[ch * 256 + wid * 16 + r];
    asm volatile("" :: "v"(bias1[0]), "v"(bias1[1]), "v"(bias2));

    // ---- stage z: 32x64 f32 -> bf16 swizzled (2 elems/thread) ----
    {
        int i = tid * 2;
        int row = i >> 6, col = i & 63;
        float2 v = *(const float2*)(z + (size_t)(bm + row) * DD + col);
        st_swz(zt, row, col,     64, v.x);
        st_swz(zt, row, col + 1, 64, v.y);
    }

    // ---- L1 prefetch: wave strip = 32 cols, 2 entries (K=64) ----
    short8 q0, q1, q2, q3, p0, p1;
    const bf16* Wb1 = W1p + (size_t)wid * 2048 + laneE;
    GLD2(q0, q1, Wb1);
    GLD2(p0, p1, Wb1 + 1024);
    LGKMBAR();    // zt visible; L1 weight loads stay in flight

    // ---- L1: h1 = tanh(z @ W1 + b1eff); a = 1-h1^2 (2 rowgroups) ----
    f32x4 acc1[2][2] = {};    // [g][f]
    WAITV(2);
#pragma unroll
    for (int g = 0; g < 2; ++g) {
        short8 av = *(const short8*)(zt + (g * 16 + r) * 64 + ((kq ^ rx) << 3));
        acc1[g][0] = __builtin_amdgcn_mfma_f32_16x16x32_bf16(av, q0, acc1[g][0], 0, 0, 0);
        acc1[g][1] = __builtin_amdgcn_mfma_f32_16x16x32_bf16(av, q1, acc1[g][1], 0, 0, 0);
    }
    WAITV(0);
#pragma unroll
    for (int g = 0; g < 2; ++g) {
        short8 av = *(const short8*)(zt + (g * 16 + r) * 64 + (((4 + kq) ^ rx) << 3));
        acc1[g][0] = __builtin_amdgcn_mfma_f32_16x16x32_bf16(av, p0, acc1[g][0], 0, 0, 0);
        acc1[g][1] = __builtin_amdgcn_mfma_f32_16x16x32_bf16(av, p1, acc1[g][1], 0, 0, 0);
    }
    // merged-loop prologue: 3 pairs (W2,Pp interleaved) = 6 loads in flight
    short8 rbW[4], rbP[4];
    const bf16* Wb2 = W2p + (size_t)(ch * 16 + wid) * 8192 + laneE;
    const bf16* WbE = Pp  + (size_t)(ch * 16 + wid) * 8192 + laneE;
    GLD1(rbW[0], Wb2);        GLD1(rbP[0], WbE);
    GLD1(rbW[1], Wb2 + 512);  GLD1(rbP[1], WbE + 512);
    GLD1(rbW[2], Wb2 + 1024); GLD1(rbP[2], WbE + 1024);
    // L1 epilogue (hides prologue latency)
#pragma unroll
    for (int g = 0; g < 2; ++g)
#pragma unroll
        for (int f = 0; f < 2; ++f) {
            int col = wid * 32 + f * 16 + r;
#pragma unroll
            for (int v = 0; v < 4; ++v) {
                int row = g * 16 + kq * 4 + v;
                float h = tanh_fast(acc1[g][f][v] + bias1[f]);
                st_swz(h1, row, col, 512, h);
                st_swz(at, row, col, 512, fmaf(-h, h, 1.0f));
            }
        }
    LGKMBAR();    // h1/at visible; ring loads stay in flight

    // ---- merged L2 || E: one 16-step loop, 2 streams, 4 MFMA/step ----
    f32x4 acc2[2] = {};   // h1 @ W2
    f32x4 accE[2] = {};   // at @ P
#pragma unroll
    for (int s = 0; s < 16; ++s) {
        // hoisted A-fragment ds_reads (latency overlaps the vmcnt stall)
        int co = (((s * 4 + kq) ^ rx) << 3);
        short8 a1v[2], aav[2];
#pragma unroll
        for (int g = 0; g < 2; ++g) {
            a1v[g] = *(const short8*)(h1 + (g * 16 + r) * 512 + co);
            aav[g] = *(const short8*)(at + (g * 16 + r) * 512 + co);
        }
        if (s + 3 < 16) {
            GLD1(rbW[(s + 3) & 3], Wb2 + (s + 3) * 512);
            GLD1(rbP[(s + 3) & 3], WbE + (s + 3) * 512);
            WAITV(6);
        } else if (s + 2 < 16) { WAITV(4); }
        else if (s + 1 < 16)   { WAITV(2); }
        else                   { WAITV(0); }
#pragma unroll
        for (int g = 0; g < 2; ++g) {
            acc2[g] = __builtin_amdgcn_mfma_f32_16x16x32_bf16(a1v[g], rbW[s & 3], acc2[g], 0, 0, 0);
            accE[g] = __builtin_amdgcn_mfma_f32_16x16x32_bf16(aav[g], rbP[s & 3], accE[g], 0, 0, 0);
        }
    }
    // epilogue: h2 + bsq from acc2; L3 prefetch; trace from accE*bsq
    f32x4 bsq[2];
    {
        int colL = wid * 16 + r;
#pragma unroll
        for (int g = 0; g < 2; ++g)
#pragma unroll
            for (int v = 0; v < 4; ++v) {
                int row = g * 16 + kq * 4 + v;
                float h = tanh_fast(acc2[g][v] + bias2);
                st_swz(h2, row, colL, 256, h);
                bsq[g][v] = fmaf(-h, h, 1.0f);
            }
        const int kw = wid & 7;
        const bf16* Wb3 = W3p + (size_t)(ch * 8 + kw) * 2048 + laneE;
        GLD4(q0, q1, q2, q3, Wb3);
#pragma unroll
        for (int g = 0; g < 2; ++g)
#pragma unroll
            for (int v = 0; v < 4; ++v) {
                float p = accE[g][v] * bsq[g][v];
                p += __shfl_xor(p, 1);
                p += __shfl_xor(p, 2);
                p += __shfl_xor(p, 4);
                p += __shfl_xor(p, 8);
                if (r == 0) trp[wid * 32 + g * 16 + kq * 4 + v] = p;
            }
    }
    LGKMBAR();    // h2/trp visible; h1/at reads done -> vp overlay safe

    // ---- L3: v-partial = h2 @ W3 (this half's k); 8 kw x 2 row-halves ----
    {
        const int kw = wid & 7, rp = wid >> 3;
        f32x4 c0 = {}, c1 = {}, c2 = {}, c3 = {};
        short8 av = *(const short8*)(h2 + (rp * 16 + r) * 256 + (((kw * 4 + kq) ^ rx) << 3));
        WAITV(0);
        c0 = __builtin_amdgcn_mfma_f32_16x16x32_bf16(av, q0, c0, 0, 0, 0);
        c1 = __builtin_amdgcn_mfma_f32_16x16x32_bf16(av, q1, c1, 0, 0, 0);
        c2 = __builtin_amdgcn_mfma_f32_16x16x32_bf16(av, q2, c2, 0, 0, 0);
        c3 = __builtin_amdgcn_mfma_f32_16x16x32_bf16(av, q3, c3, 0, 0, 0);
#pragma unroll
        for (int v = 0; v < 4; ++v) {
            int row = rp * 16 + kq * 4 + v;
            vp[kw * 2048 + row * 64 + 0 * 16 + r] = c0[v];
            vp[kw * 2048 + row * 64 + 1 * 16 + r] = c1[v];
            vp[kw * 2048 + row * 64 + 2 * 16 + r] = c2[v];
            vp[kw * 2048 + row * 64 + 3 * 16 + r] = c3[v];
        }
    }
    LGKMBAR();

    // ---- final: reduce 8 k-chunk partials; atomicAdd v and trace ----
#pragma unroll
    for (int it = 0; it < 2; ++it) {
        int i = it * 1024 + tid;
        int row = i >> 6, col = i & 63;
        float s = 0.f;
#pragma unroll
        for (int kw = 0; kw < 8; ++kw) s += vp[kw * 2048 + i];
        atomicAdd(outV + (size_t)(bm + row) * DD + col, s);
    }
    if (tid < 32) {
        float s = 0.f;
#pragma unroll
        for (int w = 0; w < 16; ++w) s += trp[w * 32 + tid];
        atomicAdd(outTr + bm + tid, -s);
    }
}

extern "C" void kernel_launch(void* const* d_in, const int* in_sizes, int n_in,
                              void* d_out, int out_size, void* d_ws, size_t ws_size,
                              hipStream_t stream)
{
    const float* z  = (const float*)d_in[0];
    const float* t  = (const float*)d_in[2];
    const float* W1 = (const float*)d_in[3];
    const float* b1 = (const float*)d_in[4];
    const float* W2 = (const float*)d_in[5];
    const float* b2 = (const float*)d_in[6];
    const float* W3 = (const float*)d_in[7];
    const float* b3 = (const float*)d_in[8];
    float* out = (float*)d_out;                 // v [4096*64] then dlogp [4096]
    float* out_tr = out + (size_t)BB * DD;

    char* w = (char*)d_ws;
    auto alloc = [&](size_t bytes) {
        char* p = w;
        w += (bytes + 255) & ~(size_t)255;
        return p;
    };
    bf16* W1p   = (bf16*)alloc((size_t)64  * 512 * 2);
    bf16* W2p   = (bf16*)alloc((size_t)512 * 512 * 2);
    bf16* W3p   = (bf16*)alloc((size_t)64  * 512 * 2);
    bf16* Pp    = (bf16*)alloc((size_t)512 * 512 * 2);
    float* b1eff = (float*)alloc((size_t)HH * 4);

    // prep: packs + P + b1eff + output init (v=b3 broadcast, trace=0)
    prep_kernel<<<549, 256, 0, stream>>>(t, W1, b1, W2, W3, b3,
                                         W1p, W2p, W3p, Pp, b1eff, out);
    fused_rows<<<128 * 2, 1024, 0, stream>>>(z, W1p, W2p, W3p, Pp,
                                             b1eff, b2, out, out_tr);
}